// Round 13
// baseline (63.582 us; speedup 1.0000x reference)
//
#include <hip/hip_runtime.h>

// KnnConvUnit: B=4, N=8192, K=16, C=64, HID=OUT=128.
// out[b,n,:] = (max_k relu(relu(x@W1+b1)@W2+b2)) @ W3 + b3
//   x=[f,knn,knn-f] -> h1 = relu(knn@Bm + fa),  fa = f@Aw + b1  (fA split)
//   Bm = W1[64:128]+W1[128:192], Aw = W1[0:64]-W1[128:192]
// v_mfma_f32_16x16x32_f16, shared k-permutation kappa(g,j)=16*(j>>2)+4g+(j&3)
// Round-13 = round-12 per-wave body, TWO 16-pt groups per 1024-thread block:
//   waves 0-7 -> group A, waves 8-15 -> group B; ONE shared wbuf (48KB),
//   per-half fabuf/pooled. LDS 74.2KB -> 2 blocks/CU = 32 waves/CU (2x TLP,
//   the only untried lever: r2/r10/r12 all ~53-55us regardless of work,
//   so the bound is per-block latency x residency). VGPR must stay <=64.

#define BB 4
#define NN 8192
#define KK 16
#define CC 64
#define HH 128

typedef _Float16 f16;
typedef __fp16 h16x2 __attribute__((ext_vector_type(2)));   // cvt_pkrtz return type
typedef _Float16 f16x8 __attribute__((ext_vector_type(8)));
typedef float f32x4 __attribute__((ext_vector_type(4)));

#define MFMA16(a, b, c) __builtin_amdgcn_mfma_f32_16x16x32_f16(a, b, c, 0, 0, 0)

static __device__ __forceinline__ f16x8 cvt8(f32x4 a0, f32x4 a1) {
  h16x2 c0 = __builtin_amdgcn_cvt_pkrtz(a0[0], a0[1]);
  h16x2 c1 = __builtin_amdgcn_cvt_pkrtz(a0[2], a0[3]);
  h16x2 c2 = __builtin_amdgcn_cvt_pkrtz(a1[0], a1[1]);
  h16x2 c3 = __builtin_amdgcn_cvt_pkrtz(a1[2], a1[3]);
  f16x8 v;
  v[0] = (f16)c0[0]; v[1] = (f16)c0[1]; v[2] = (f16)c1[0]; v[3] = (f16)c1[1];
  v[4] = (f16)c2[0]; v[5] = (f16)c2[1]; v[6] = (f16)c3[0]; v[7] = (f16)c3[1];
  return v;
}

// LDS-only barrier: does NOT drain vmcnt -> global loads stay in flight.
static __device__ __forceinline__ void lds_barrier() {
  asm volatile("s_waitcnt lgkmcnt(0)" ::: "memory");
  __builtin_amdgcn_s_barrier();
  __builtin_amdgcn_sched_barrier(0);
}

// ---------------- prep: pack weights, fragment-linear f16, kappa k-order ----
// fid 0..15 : Bm A-frags (ht*2+kt)     | fid 16..47: W2 (16+h2t*4+kt)
// fid 48..63: Aw A-frags (48+ht*2+kt)  | fid 64..95: W3 (64+ot*4+kt)
__global__ void prep_pack(const float* __restrict__ W1, const float* __restrict__ W2,
                          const float* __restrict__ W3, f16* __restrict__ ws) {
  int fid = blockIdx.x * 8 + (threadIdx.x >> 6);
  int l = threadIdx.x & 63;
  int g = l >> 4, r = l & 15;
  f16x8 v;
#pragma unroll
  for (int j = 0; j < 8; ++j) {
    int kl = 16 * (j >> 2) + 4 * g + (j & 3);   // kappa(g,j)
    float x;
    if (fid < 16) {
      int ht = fid >> 1, kt = fid & 1, h = ht * 16 + r, k = kt * 32 + kl;
      x = W1[(64 + k) * HH + h] + W1[(128 + k) * HH + h];      // Bm
    } else if (fid < 48) {
      int t = fid - 16, h2t = t >> 2, kt = t & 3;
      x = W2[(kt * 32 + kl) * HH + h2t * 16 + r];
    } else if (fid < 64) {
      int t = fid - 48, ht = t >> 1, kt = t & 1, h = ht * 16 + r, k = kt * 32 + kl;
      x = W1[k * HH + h] - W1[(128 + k) * HH + h];             // Aw
    } else {
      int t = fid - 64, ot = t >> 2, kt = t & 3;
      x = W3[(kt * 32 + kl) * HH + ot * 16 + r];
    }
    v[j] = (f16)x;
  }
  *(f16x8*)(ws + (size_t)fid * 512 + l * 8) = v;
}

// ------------- main: 32 pts/block, 16 waves (2 halves x 8), 2 pts/wave -------
// LDS: wbuf 48 frags (48KB, shared) | fabuf [2][16][132] f32 (16896B)
//      pooled [2][4 frags] (8192B)  -> total 74240 B -> 2 blocks/CU, 32 w/CU
__global__ __launch_bounds__(1024, 4) void knn_main(
    const float* __restrict__ f, const int* __restrict__ knn,
    const float* __restrict__ b1, const float* __restrict__ b2,
    const float* __restrict__ b3, const f16* __restrict__ ws,
    float* __restrict__ out) {
  extern __shared__ char smem[];
  f16* wbuf = (f16*)smem;                       // 48*512 f16
  float* fabuf = (float*)(wbuf + 48 * 512);     // [2][16][132] f32
  f16* pooled = (f16*)(fabuf + 2 * 16 * 132);   // [2][2048] f16

  const int tid = threadIdx.x;
  const int wave = tid >> 6, lane = tid & 63;
  const int g = lane >> 4, r = lane & 15;
  const int half = wave >> 3, wq = wave & 7;

  // XCD-aware swizzle: 1024 wgs, 8 XCDs -> each XCD owns 128 contiguous wgs
  const int wg = (blockIdx.x & 7) * 128 + (blockIdx.x >> 3);
  const int b = wg >> 8;                 // 256 wgs per batch
  const int n0 = (wg & 255) * 32 + half * 16;
  const float* fb = f + (size_t)b * NN * CC;
  const int p0 = wq * 2;

  float* fab = fabuf + half * 16 * 132;
  f16* poo = pooled + half * 2048;

  // --- issue knn index loads first (head of the longest chain) ---
  int nidx[2];
#pragma unroll
  for (int pp = 0; pp < 2; ++pp)
    nidx[pp] = knn[(size_t)(b * NN + n0 + p0 + pp) * KK + r];

  // --- issue fA point-rows (col r = point n0+r) + Aw frags (L2-hot) ---
  const float* fo = fb + (size_t)(n0 + r) * CC;
  f32x4 rawF[2][2];
#pragma unroll
  for (int kt = 0; kt < 2; ++kt) {
    rawF[kt][0] = *(const f32x4*)(fo + kt * 32 + 4 * g);
    rawF[kt][1] = *(const f32x4*)(fo + kt * 32 + 4 * g + 16);
  }
  f16x8 aw[2];
#pragma unroll
  for (int kt = 0; kt < 2; ++kt)
    aw[kt] = *(const f16x8*)(ws + (size_t)(48 + wq * 2 + kt) * 512 + lane * 8);

  // --- stage 48 weight frags (Bm+W2) into LDS: 3072 slots / 1024 thr ---
  f16x8 st[3];
#pragma unroll
  for (int i = 0; i < 3; ++i)
    st[i] = *(const f16x8*)(ws + (size_t)(i * 1024 + tid) * 8);
#pragma unroll
  for (int i = 0; i < 3; ++i)
    *(f16x8*)(wbuf + (size_t)(i * 1024 + tid) * 8) = st[i];

  // --- issue neighbor gathers (scattered; cvt deferred past barrier) ---
  f32x4 rawN[2][2][2];
#pragma unroll
  for (int pp = 0; pp < 2; ++pp) {
    const float* fn = fb + (size_t)nidx[pp] * CC;
#pragma unroll
    for (int kt = 0; kt < 2; ++kt) {
      rawN[pp][kt][0] = *(const f32x4*)(fn + kt * 32 + 4 * g);
      rawN[pp][kt][1] = *(const f32x4*)(fn + kt * 32 + 4 * g + 16);
    }
  }

  // --- fA: fa[wq's h-tile][all 16 pts of this half] = f@Aw + b1 -> fab ---
  {
    f32x4 acc = {0.f, 0.f, 0.f, 0.f};
#pragma unroll
    for (int kt = 0; kt < 2; ++kt) {
      f16x8 bfa = cvt8(rawF[kt][0], rawF[kt][1]);
      acc = MFMA16(aw[kt], bfa, acc);
    }
    f32x4 b1v = *(const f32x4*)(b1 + wq * 16 + g * 4);
    f32x4 fa;
#pragma unroll
    for (int i = 0; i < 4; ++i) fa[i] = acc[i] + b1v[i];
    *(f32x4*)(fab + r * 132 + wq * 16 + g * 4) = fa;
  }

  lds_barrier();   // (1) wbuf + fabuf ready; neighbor gathers still in flight

  // --- convert gathered neighbor rows ---
  f16x8 bf[2][2];
#pragma unroll
  for (int pp = 0; pp < 2; ++pp)
#pragma unroll
    for (int kt = 0; kt < 2; ++kt)
      bf[pp][kt] = cvt8(rawN[pp][kt][0], rawN[pp][kt][1]);

  // --- L1: C[h][nbr] = Bm^T x knn (K=64), + fa broadcast, relu -> h1 regs ---
  f16x8 h1f[2][4];
#pragma unroll
  for (int ht = 0; ht < 8; ++ht) {
    f32x4 acc[2] = {{0.f, 0.f, 0.f, 0.f}, {0.f, 0.f, 0.f, 0.f}};
#pragma unroll
    for (int kt = 0; kt < 2; ++kt) {
      f16x8 wfrag = *(const f16x8*)(wbuf + (size_t)(ht * 2 + kt) * 512 + lane * 8);
      acc[0] = MFMA16(wfrag, bf[0][kt], acc[0]);
      acc[1] = MFMA16(wfrag, bf[1][kt], acc[1]);
    }
    f32x4 fa0 = *(const f32x4*)(fab + (p0 + 0) * 132 + ht * 16 + g * 4);
    f32x4 fa1 = *(const f32x4*)(fab + (p0 + 1) * 132 + ht * 16 + g * 4);
#pragma unroll
    for (int pp = 0; pp < 2; ++pp) {
      const f32x4& fa = pp ? fa1 : fa0;
      float x0 = acc[pp][0] + fa[0]; x0 = x0 > 0.f ? x0 : 0.f;
      float x1 = acc[pp][1] + fa[1]; x1 = x1 > 0.f ? x1 : 0.f;
      float x2 = acc[pp][2] + fa[2]; x2 = x2 > 0.f ? x2 : 0.f;
      float x3 = acc[pp][3] + fa[3]; x3 = x3 > 0.f ? x3 : 0.f;
      h16x2 lo = __builtin_amdgcn_cvt_pkrtz(x0, x1);
      h16x2 hi = __builtin_amdgcn_cvt_pkrtz(x2, x3);
      h1f[pp][ht >> 1][(ht & 1) * 4 + 0] = (f16)lo[0];
      h1f[pp][ht >> 1][(ht & 1) * 4 + 1] = (f16)lo[1];
      h1f[pp][ht >> 1][(ht & 1) * 4 + 2] = (f16)hi[0];
      h1f[pp][ht >> 1][(ht & 1) * 4 + 3] = (f16)hi[1];
    }
  }

  // --- L2: C[nbr][h2] = h1 x W2 (frags 16..47); pool = 3 v_max + 2 shfl ---
#pragma unroll
  for (int h2t = 0; h2t < 8; ++h2t) {
    f32x4 c0 = {0.f, 0.f, 0.f, 0.f}, c1 = {0.f, 0.f, 0.f, 0.f};
#pragma unroll
    for (int kt = 0; kt < 4; ++kt) {
      f16x8 w2f = *(const f16x8*)(wbuf + (size_t)(16 + h2t * 4 + kt) * 512 + lane * 8);
      c0 = MFMA16(h1f[0][kt], w2f, c0);
      c1 = MFMA16(h1f[1][kt], w2f, c1);
    }
    float b2v = b2[h2t * 16 + r];
#pragma unroll
    for (int pp = 0; pp < 2; ++pp) {
      f32x4 cc = pp ? c1 : c0;
      float m = fmaxf(fmaxf(cc[0], cc[1]), fmaxf(cc[2], cc[3]));
      m = fmaxf(m, __shfl_xor(m, 16, 64));
      m = fmaxf(m, __shfl_xor(m, 32, 64));
      float x = m + b2v;
      f16 pv = (f16)(x > 0.f ? x : 0.f);
      if (g == 0) {
        // dest: frag h2t>>1, lane slot (r>>2)*16 + p, elem (h2t&1)*4 + (r&3)
        poo[(h2t >> 1) * 512 + ((r >> 2) * 16 + p0 + pp) * 8 +
            (h2t & 1) * 4 + (r & 3)] = pv;
      }
    }
  }

  // --- prefetch W3 frags (global, L2-hot) so they cross barrier in flight ---
  f16x8 w3f[4];
#pragma unroll
  for (int kt = 0; kt < 4; ++kt)
    w3f[kt] = *(const f16x8*)(ws + (size_t)(64 + wq * 4 + kt) * 512 + lane * 8);

  lds_barrier();   // (2) pooled ready (cross-wave, LDS-only)

  // --- L3: C[od][pt] = W3^T x pooled; wave owns od-tile = wq ---
  {
    f32x4 a3 = {0.f, 0.f, 0.f, 0.f};
#pragma unroll
    for (int kt = 0; kt < 4; ++kt) {
      f16x8 pf = *(const f16x8*)(poo + kt * 512 + lane * 8);
      a3 = MFMA16(w3f[kt], pf, a3);
    }
    f32x4 b3v = *(const f32x4*)(b3 + wq * 16 + g * 4);
    f32x4 o;
#pragma unroll
    for (int i = 0; i < 4; ++i) o[i] = a3[i] + b3v[i];
    *(f32x4*)(out + ((size_t)b * NN + n0 + r) * HH + wq * 16 + g * 4) = o;
  }
}

extern "C" void kernel_launch(void* const* d_in, const int* in_sizes, int n_in,
                              void* d_out, int out_size, void* d_ws, size_t ws_size,
                              hipStream_t stream) {
  const float* f = (const float*)d_in[0];
  const int* knn = (const int*)d_in[1];
  const float* W1 = (const float*)d_in[2];
  const float* b1 = (const float*)d_in[3];
  const float* W2 = (const float*)d_in[4];
  const float* b2 = (const float*)d_in[5];
  const float* W3 = (const float*)d_in[6];
  const float* b3 = (const float*)d_in[7];
  float* outp = (float*)d_out;
  f16* wsp = (f16*)d_ws;   // 96 frags * 1KB = 96KB scratch

  (void)hipFuncSetAttribute((const void*)knn_main,
                            hipFuncAttributeMaxDynamicSharedMemorySize, 74240);

  prep_pack<<<12, 512, 0, stream>>>(W1, W2, W3, wsp);
  // 32 pts/block (16 waves x 2) -> grid = 32768/32 = 1024
  knn_main<<<(BB * NN) / 32, 1024, 74240, stream>>>(f, knn, b1, b2, b3, wsp, outp);
}

// Round 15
// 48.986 us; speedup vs baseline: 1.2980x; 1.2980x over previous
//
#include <hip/hip_runtime.h>

// KnnConvUnit: B=4, N=8192, K=16, C=64, HID=OUT=128.
// out[b,n,:] = (max_k relu(relu(x@W1+b1)@W2+b2)) @ W3 + b3
//   x=[f,knn,knn-f] -> h1 = relu(knn@Bm + fa),  fa = f@Aw + b1  (fA split)
//   Bm = W1[64:128]+W1[128:192], Aw = W1[0:64]-W1[128:192]
// v_mfma_f32_16x16x32_f16, shared k-permutation kappa(g,j)=16*(j>>2)+4g+(j&3)
// Round-15 = round-14 with the neighbor batch-offset fix:
//   fh is global-row indexed; neighbor read must be fh[(b*NN + nidx)*CC]
//   (r14 dropped b*NN -> batches 1-3 gathered batch-0 rows, absmax 1.14).
//   prep_f16 pre-converts f to f16 in fragment lane order (4MB in d_ws):
//   scattered loads halve (gather 8->4, own 4->2 insts), gather cvt VALU gone.
//   Runtime ws_size check; falls back to exact r12 path if scratch small.

#define BB 4
#define NN 8192
#define KK 16
#define CC 64
#define HH 128

typedef _Float16 f16;
typedef __fp16 h16x2 __attribute__((ext_vector_type(2)));   // cvt_pkrtz return type
typedef _Float16 f16x8 __attribute__((ext_vector_type(8)));
typedef float f32x4 __attribute__((ext_vector_type(4)));

#define MFMA16(a, b, c) __builtin_amdgcn_mfma_f32_16x16x32_f16(a, b, c, 0, 0, 0)

static __device__ __forceinline__ f16x8 cvt8(f32x4 a0, f32x4 a1) {
  h16x2 c0 = __builtin_amdgcn_cvt_pkrtz(a0[0], a0[1]);
  h16x2 c1 = __builtin_amdgcn_cvt_pkrtz(a0[2], a0[3]);
  h16x2 c2 = __builtin_amdgcn_cvt_pkrtz(a1[0], a1[1]);
  h16x2 c3 = __builtin_amdgcn_cvt_pkrtz(a1[2], a1[3]);
  f16x8 v;
  v[0] = (f16)c0[0]; v[1] = (f16)c0[1]; v[2] = (f16)c1[0]; v[3] = (f16)c1[1];
  v[4] = (f16)c2[0]; v[5] = (f16)c2[1]; v[6] = (f16)c3[0]; v[7] = (f16)c3[1];
  return v;
}

// LDS-only barrier: does NOT drain vmcnt -> global loads stay in flight.
static __device__ __forceinline__ void lds_barrier() {
  asm volatile("s_waitcnt lgkmcnt(0)" ::: "memory");
  __builtin_amdgcn_s_barrier();
  __builtin_amdgcn_sched_barrier(0);
}

// ---------------- prep: pack weights, fragment-linear f16, kappa k-order ----
// fid 0..15 : Bm A-frags (ht*2+kt)     | fid 16..47: W2 (16+h2t*4+kt)
// fid 48..63: Aw A-frags (48+ht*2+kt)  | fid 64..95: W3 (64+ot*4+kt)
__global__ void prep_pack(const float* __restrict__ W1, const float* __restrict__ W2,
                          const float* __restrict__ W3, f16* __restrict__ ws) {
  int fid = blockIdx.x * 8 + (threadIdx.x >> 6);
  int l = threadIdx.x & 63;
  int g = l >> 4, r = l & 15;
  f16x8 v;
#pragma unroll
  for (int j = 0; j < 8; ++j) {
    int kl = 16 * (j >> 2) + 4 * g + (j & 3);   // kappa(g,j)
    float x;
    if (fid < 16) {
      int ht = fid >> 1, kt = fid & 1, h = ht * 16 + r, k = kt * 32 + kl;
      x = W1[(64 + k) * HH + h] + W1[(128 + k) * HH + h];      // Bm
    } else if (fid < 48) {
      int t = fid - 16, h2t = t >> 2, kt = t & 3;
      x = W2[(kt * 32 + kl) * HH + h2t * 16 + r];
    } else if (fid < 64) {
      int t = fid - 48, ht = t >> 1, kt = t & 1, h = ht * 16 + r, k = kt * 32 + kl;
      x = W1[k * HH + h] - W1[(128 + k) * HH + h];             // Aw
    } else {
      int t = fid - 64, ot = t >> 2, kt = t & 3;
      x = W3[(kt * 32 + kl) * HH + ot * 16 + r];
    }
    v[j] = (f16)x;
  }
  *(f16x8*)(ws + (size_t)fid * 512 + l * 8) = v;
}

// ---------------- prep2: f -> f16, pre-permuted to fragment lane order -------
// fh[row*64 + kt*32 + g*8 + j] = (f16) f[row*64 + kt*32 + kappa(g,j)]
// kappa j<4 -> 4g+j (contig), j>=4 -> 16+4g+(j-4) (contig). Coalesced store.
__global__ void prep_f16(const float* __restrict__ f, f16* __restrict__ fh) {
  int chunk = blockIdx.x * 256 + threadIdx.x;   // 0 .. BB*NN*8-1
  int row = chunk >> 3;
  int kt = (chunk >> 2) & 1;
  int g = chunk & 3;
  const float* src = f + (size_t)row * CC + kt * 32;
  f32x4 a0 = *(const f32x4*)(src + 4 * g);
  f32x4 a1 = *(const f32x4*)(src + 16 + 4 * g);
  f16x8 v;
#pragma unroll
  for (int j = 0; j < 4; ++j) { v[j] = (f16)a0[j]; v[4 + j] = (f16)a1[j]; }
  *(f16x8*)(fh + (size_t)row * CC + kt * 32 + g * 8) = v;
}

// ---------------- main: 16 points/block, 8 waves, 2 pts/wave ----------------
// LDS: wbuf 48 frags (Bm+W2, 48KB) | fabuf [16][132] f32 (8448B)
//      pooled 4 frags (4KB)   -> total 61696 B -> 2 blocks/CU
template <bool F16G>
__global__ __launch_bounds__(512, 4) void knn_main(
    const float* __restrict__ f, const int* __restrict__ knn,
    const float* __restrict__ b1, const float* __restrict__ b2,
    const float* __restrict__ b3, const f16* __restrict__ ws,
    const f16* __restrict__ fh, float* __restrict__ out) {
  extern __shared__ char smem[];
  f16* wbuf = (f16*)smem;                       // 48*512 f16
  float* fabuf = (float*)(wbuf + 48 * 512);     // [16][132] f32
  f16* pooled = (f16*)(fabuf + 16 * 132);       // 4*512 f16

  const int tid = threadIdx.x;
  const int wave = tid >> 6, lane = tid & 63;
  const int g = lane >> 4, r = lane & 15;

  // XCD-aware swizzle: 2048 wgs, 8 XCDs -> each XCD owns 256 contiguous wgs
  const int wg = (blockIdx.x & 7) * 256 + (blockIdx.x >> 3);
  const int b = wg >> 9;
  const int n0 = (wg & 511) * 16;
  const float* fb = f + (size_t)b * NN * CC;
  const f16* fhb = fh + (size_t)b * NN * CC;    // batch-local f16 table
  const int p0 = wave * 2;

  // --- issue knn index loads first (head of the longest chain) ---
  int nidx[2];
#pragma unroll
  for (int pp = 0; pp < 2; ++pp)
    nidx[pp] = knn[(size_t)(b * NN + n0 + p0 + pp) * KK + r];

  // --- own-point rows (B col r = point n0+r) + Aw frags (L2-hot) ---
  f16x8 bfa[2];          // fA B-frags (own rows)
  f32x4 rawF[2][2];      // f32 fallback
  if constexpr (F16G) {
    const f16* fo16 = fhb + (size_t)(n0 + r) * CC;
    bfa[0] = *(const f16x8*)(fo16 + g * 8);
    bfa[1] = *(const f16x8*)(fo16 + 32 + g * 8);
  } else {
    const float* fo = fb + (size_t)(n0 + r) * CC;
#pragma unroll
    for (int kt = 0; kt < 2; ++kt) {
      rawF[kt][0] = *(const f32x4*)(fo + kt * 32 + 4 * g);
      rawF[kt][1] = *(const f32x4*)(fo + kt * 32 + 4 * g + 16);
    }
  }
  f16x8 aw[2];
#pragma unroll
  for (int kt = 0; kt < 2; ++kt)
    aw[kt] = *(const f16x8*)(ws + (size_t)(48 + wave * 2 + kt) * 512 + lane * 8);

  // --- stage 48 weight frags (Bm+W2) into LDS, reg-staged, linear ---
  f16x8 st[6];
#pragma unroll
  for (int i = 0; i < 6; ++i)
    st[i] = *(const f16x8*)(ws + (size_t)(i * 512 + tid) * 8);
#pragma unroll
  for (int i = 0; i < 6; ++i)
    *(f16x8*)(wbuf + (size_t)(i * 512 + tid) * 8) = st[i];

  // --- neighbor gathers (scattered) ---
  f16x8 bf[2][2];
  f32x4 rawN[2][2][2];
  if constexpr (F16G) {
    // direct f16 frag loads (batch-local table!); consumed after barrier
#pragma unroll
    for (int pp = 0; pp < 2; ++pp) {
      const f16* fn16 = fhb + (size_t)nidx[pp] * CC;
#pragma unroll
      for (int kt = 0; kt < 2; ++kt)
        bf[pp][kt] = *(const f16x8*)(fn16 + kt * 32 + g * 8);
    }
  } else {
#pragma unroll
    for (int pp = 0; pp < 2; ++pp) {
      const float* fn = fb + (size_t)nidx[pp] * CC;
#pragma unroll
      for (int kt = 0; kt < 2; ++kt) {
        rawN[pp][kt][0] = *(const f32x4*)(fn + kt * 32 + 4 * g);
        rawN[pp][kt][1] = *(const f32x4*)(fn + kt * 32 + 4 * g + 16);
      }
    }
  }

  // --- fA: fa[wave's h-tile][all 16 pts] = f@Aw + b1 -> fabuf ---
  {
    f32x4 acc = {0.f, 0.f, 0.f, 0.f};
    if constexpr (F16G) {
      acc = MFMA16(aw[0], bfa[0], acc);
      acc = MFMA16(aw[1], bfa[1], acc);
    } else {
#pragma unroll
      for (int kt = 0; kt < 2; ++kt) {
        f16x8 bfa2 = cvt8(rawF[kt][0], rawF[kt][1]);
        acc = MFMA16(aw[kt], bfa2, acc);
      }
    }
    f32x4 b1v = *(const f32x4*)(b1 + wave * 16 + g * 4);
    f32x4 fa;
#pragma unroll
    for (int i = 0; i < 4; ++i) fa[i] = acc[i] + b1v[i];
    *(f32x4*)(fabuf + r * 132 + wave * 16 + g * 4) = fa;
  }

  lds_barrier();   // (1) wbuf + fabuf ready; neighbor gathers still in flight

  if constexpr (!F16G) {
#pragma unroll
    for (int pp = 0; pp < 2; ++pp)
#pragma unroll
      for (int kt = 0; kt < 2; ++kt)
        bf[pp][kt] = cvt8(rawN[pp][kt][0], rawN[pp][kt][1]);
  }

  // --- L1: C[h][nbr] = Bm^T x knn (K=64), + fa broadcast, relu -> h1 regs ---
  f16x8 h1f[2][4];
#pragma unroll
  for (int ht = 0; ht < 8; ++ht) {
    f32x4 acc[2] = {{0.f, 0.f, 0.f, 0.f}, {0.f, 0.f, 0.f, 0.f}};
#pragma unroll
    for (int kt = 0; kt < 2; ++kt) {
      f16x8 wfrag = *(const f16x8*)(wbuf + (size_t)(ht * 2 + kt) * 512 + lane * 8);
      acc[0] = MFMA16(wfrag, bf[0][kt], acc[0]);
      acc[1] = MFMA16(wfrag, bf[1][kt], acc[1]);
    }
    f32x4 fa0 = *(const f32x4*)(fabuf + (p0 + 0) * 132 + ht * 16 + g * 4);
    f32x4 fa1 = *(const f32x4*)(fabuf + (p0 + 1) * 132 + ht * 16 + g * 4);
#pragma unroll
    for (int pp = 0; pp < 2; ++pp) {
      const f32x4& fa = pp ? fa1 : fa0;
      float x0 = acc[pp][0] + fa[0]; x0 = x0 > 0.f ? x0 : 0.f;
      float x1 = acc[pp][1] + fa[1]; x1 = x1 > 0.f ? x1 : 0.f;
      float x2 = acc[pp][2] + fa[2]; x2 = x2 > 0.f ? x2 : 0.f;
      float x3 = acc[pp][3] + fa[3]; x3 = x3 > 0.f ? x3 : 0.f;
      h16x2 lo = __builtin_amdgcn_cvt_pkrtz(x0, x1);
      h16x2 hi = __builtin_amdgcn_cvt_pkrtz(x2, x3);
      h1f[pp][ht >> 1][(ht & 1) * 4 + 0] = (f16)lo[0];
      h1f[pp][ht >> 1][(ht & 1) * 4 + 1] = (f16)lo[1];
      h1f[pp][ht >> 1][(ht & 1) * 4 + 2] = (f16)hi[0];
      h1f[pp][ht >> 1][(ht & 1) * 4 + 3] = (f16)hi[1];
    }
  }

  // --- L2: C[nbr][h2] = h1 x W2 (frags 16..47); pool = 3 v_max + 2 shfl ---
#pragma unroll
  for (int h2t = 0; h2t < 8; ++h2t) {
    f32x4 c0 = {0.f, 0.f, 0.f, 0.f}, c1 = {0.f, 0.f, 0.f, 0.f};
#pragma unroll
    for (int kt = 0; kt < 4; ++kt) {
      f16x8 w2f = *(const f16x8*)(wbuf + (size_t)(16 + h2t * 4 + kt) * 512 + lane * 8);
      c0 = MFMA16(h1f[0][kt], w2f, c0);
      c1 = MFMA16(h1f[1][kt], w2f, c1);
    }
    float b2v = b2[h2t * 16 + r];
#pragma unroll
    for (int pp = 0; pp < 2; ++pp) {
      f32x4 cc = pp ? c1 : c0;
      float m = fmaxf(fmaxf(cc[0], cc[1]), fmaxf(cc[2], cc[3]));
      m = fmaxf(m, __shfl_xor(m, 16, 64));
      m = fmaxf(m, __shfl_xor(m, 32, 64));
      float x = m + b2v;
      f16 pv = (f16)(x > 0.f ? x : 0.f);
      if (g == 0) {
        pooled[(h2t >> 1) * 512 + ((r >> 2) * 16 + p0 + pp) * 8 +
               (h2t & 1) * 4 + (r & 3)] = pv;
      }
    }
  }

  // --- prefetch W3 frags (global, L2-hot) so they cross barrier in flight ---
  f16x8 w3f[4];
#pragma unroll
  for (int kt = 0; kt < 4; ++kt)
    w3f[kt] = *(const f16x8*)(ws + (size_t)(64 + wave * 4 + kt) * 512 + lane * 8);

  lds_barrier();   // (2) pooled ready (cross-wave, LDS-only)

  // --- L3: C[od][pt] = W3^T x pooled; wave owns od-tile = wave ---
  {
    f32x4 a3 = {0.f, 0.f, 0.f, 0.f};
#pragma unroll
    for (int kt = 0; kt < 4; ++kt) {
      f16x8 pf = *(const f16x8*)(pooled + kt * 512 + lane * 8);
      a3 = MFMA16(w3f[kt], pf, a3);
    }
    f32x4 b3v = *(const f32x4*)(b3 + wave * 16 + g * 4);
    f32x4 o;
#pragma unroll
    for (int i = 0; i < 4; ++i) o[i] = a3[i] + b3v[i];
    *(f32x4*)(out + ((size_t)b * NN + n0 + r) * HH + wave * 16 + g * 4) = o;
  }
}

extern "C" void kernel_launch(void* const* d_in, const int* in_sizes, int n_in,
                              void* d_out, int out_size, void* d_ws, size_t ws_size,
                              hipStream_t stream) {
  const float* f = (const float*)d_in[0];
  const int* knn = (const int*)d_in[1];
  const float* W1 = (const float*)d_in[2];
  const float* b1 = (const float*)d_in[3];
  const float* W2 = (const float*)d_in[4];
  const float* b2 = (const float*)d_in[5];
  const float* W3 = (const float*)d_in[6];
  const float* b3 = (const float*)d_in[7];
  float* outp = (float*)d_out;
  f16* wsp = (f16*)d_ws;                 // frags: 96KB; fh: +4MB after
  f16* fh = wsp + 96 * 512;

  const size_t need = 96 * 1024 + (size_t)BB * NN * CC * 2;

  prep_pack<<<12, 512, 0, stream>>>(W1, W2, W3, wsp);

  if (ws_size >= need) {
    (void)hipFuncSetAttribute((const void*)knn_main<true>,
                              hipFuncAttributeMaxDynamicSharedMemorySize, 61696);
    prep_f16<<<(BB * NN * 8) / 256, 256, 0, stream>>>(f, fh);
    knn_main<true><<<(BB * NN) / 16, 512, 61696, stream>>>(f, knn, b1, b2, b3,
                                                           wsp, fh, outp);
  } else {
    (void)hipFuncSetAttribute((const void*)knn_main<false>,
                              hipFuncAttributeMaxDynamicSharedMemorySize, 61696);
    knn_main<false><<<(BB * NN) / 16, 512, 61696, stream>>>(f, knn, b1, b2, b3,
                                                            wsp, fh, outp);
  }
}

// Round 16
// 44.708 us; speedup vs baseline: 1.4221x; 1.0957x over previous
//
#include <hip/hip_runtime.h>

// KnnConvUnit: B=4, N=8192, K=16, C=64, HID=OUT=128.
// out[b,n,:] = (max_k relu(relu(x@W1+b1)@W2+b2)) @ W3 + b3
//   x=[f,knn,knn-f] -> h1 = relu(knn@Bm + fa),  fa = f@Aw + b1  (fA split)
//   Bm = W1[64:128]+W1[128:192], Aw = W1[0:64]-W1[128:192]
// v_mfma_f32_16x16x32_f16, shared k-permutation kappa(g,j)=16*(j>>2)+4g+(j&3)
// Round-16 = round-15 body (48.9us champion, f16 gather table) made
// persistent, now that loop-carried prefetch state is tiny (26 VGPR f16
// vs r11's 64 f32 -> no spill mechanism):
//   * grid 512, ITERS=4 x 16 pts: weights staged once per 64 pts; aw/w3f
//     hoisted out of loop; next-iter gathers issued post-L2 (T14), latency
//     hides under pool+barrier+L3. LDS-only barriers (r10). Single-buffered
//     fabuf/pooled verified race-free (barrier(2)_i separates L1-reads from
//     fA_{i+1} writes; barrier(1)_{i+1} separates L3-reads from L2 writes).
//   * prep_pack + prep_f16 merged into ONE launch (grid 524).
//   * fallback: exact r15 one-shot f32 path if ws too small.

#define BB 4
#define NN 8192
#define KK 16
#define CC 64
#define HH 128
#define ITERS 4

typedef _Float16 f16;
typedef __fp16 h16x2 __attribute__((ext_vector_type(2)));   // cvt_pkrtz return type
typedef _Float16 f16x8 __attribute__((ext_vector_type(8)));
typedef float f32x4 __attribute__((ext_vector_type(4)));

#define MFMA16(a, b, c) __builtin_amdgcn_mfma_f32_16x16x32_f16(a, b, c, 0, 0, 0)

static __device__ __forceinline__ f16x8 cvt8(f32x4 a0, f32x4 a1) {
  h16x2 c0 = __builtin_amdgcn_cvt_pkrtz(a0[0], a0[1]);
  h16x2 c1 = __builtin_amdgcn_cvt_pkrtz(a0[2], a0[3]);
  h16x2 c2 = __builtin_amdgcn_cvt_pkrtz(a1[0], a1[1]);
  h16x2 c3 = __builtin_amdgcn_cvt_pkrtz(a1[2], a1[3]);
  f16x8 v;
  v[0] = (f16)c0[0]; v[1] = (f16)c0[1]; v[2] = (f16)c1[0]; v[3] = (f16)c1[1];
  v[4] = (f16)c2[0]; v[5] = (f16)c2[1]; v[6] = (f16)c3[0]; v[7] = (f16)c3[1];
  return v;
}

// LDS-only barrier: does NOT drain vmcnt -> global loads stay in flight.
static __device__ __forceinline__ void lds_barrier() {
  asm volatile("s_waitcnt lgkmcnt(0)" ::: "memory");
  __builtin_amdgcn_s_barrier();
  __builtin_amdgcn_sched_barrier(0);
}

// ---------------- merged prep: weights pack + f16 gather table ----------------
// blocks 0..11: weight frags (fid = blk*8 + tid>>6):
//   fid 0..15 Bm | 16..47 W2 | 48..63 Aw | 64..95 W3   (kappa k-order)
// blocks 12..523: fh[row][kt*32+g*8+j] = f16(f[row][kt*32+kappa(g,j)])
__global__ void prep_all(const float* __restrict__ f, const float* __restrict__ W1,
                         const float* __restrict__ W2, const float* __restrict__ W3,
                         f16* __restrict__ ws, f16* __restrict__ fh) {
  if (blockIdx.x < 12) {
    int fid = blockIdx.x * 8 + (threadIdx.x >> 6);
    int l = threadIdx.x & 63;
    int g = l >> 4, r = l & 15;
    f16x8 v;
#pragma unroll
    for (int j = 0; j < 8; ++j) {
      int kl = 16 * (j >> 2) + 4 * g + (j & 3);   // kappa(g,j)
      float x;
      if (fid < 16) {
        int ht = fid >> 1, kt = fid & 1, h = ht * 16 + r, k = kt * 32 + kl;
        x = W1[(64 + k) * HH + h] + W1[(128 + k) * HH + h];      // Bm
      } else if (fid < 48) {
        int t = fid - 16, h2t = t >> 2, kt = t & 3;
        x = W2[(kt * 32 + kl) * HH + h2t * 16 + r];
      } else if (fid < 64) {
        int t = fid - 48, ht = t >> 1, kt = t & 1, h = ht * 16 + r, k = kt * 32 + kl;
        x = W1[k * HH + h] - W1[(128 + k) * HH + h];             // Aw
      } else {
        int t = fid - 64, ot = t >> 2, kt = t & 3;
        x = W3[(kt * 32 + kl) * HH + ot * 16 + r];
      }
      v[j] = (f16)x;
    }
    *(f16x8*)(ws + (size_t)fid * 512 + l * 8) = v;
  } else {
    int chunk = (blockIdx.x - 12) * 512 + threadIdx.x;   // 0 .. BB*NN*8-1
    int row = chunk >> 3;
    int kt = (chunk >> 2) & 1;
    int g = chunk & 3;
    const float* src = f + (size_t)row * CC + kt * 32;
    f32x4 a0 = *(const f32x4*)(src + 4 * g);
    f32x4 a1 = *(const f32x4*)(src + 16 + 4 * g);
    f16x8 v;
#pragma unroll
    for (int j = 0; j < 4; ++j) { v[j] = (f16)a0[j]; v[4 + j] = (f16)a1[j]; }
    *(f16x8*)(fh + (size_t)row * CC + kt * 32 + g * 8) = v;
  }
}

// --------- persistent main: 64 pts/block (4 iters x 16), 8 waves ----------
// LDS: wbuf 48 frags (48KB) | fabuf [16][132] f32 (8448B) | pooled 4KB = 61696
__global__ __launch_bounds__(512, 4) void knn_pers(
    const int* __restrict__ knn, const float* __restrict__ b1,
    const float* __restrict__ b2, const float* __restrict__ b3,
    const f16* __restrict__ ws, const f16* __restrict__ fh,
    float* __restrict__ out) {
  extern __shared__ char smem[];
  f16* wbuf = (f16*)smem;                       // 48*512 f16
  float* fabuf = (float*)(wbuf + 48 * 512);     // [16][132] f32
  f16* pooled = (f16*)(fabuf + 16 * 132);       // 4*512 f16

  const int tid = threadIdx.x;
  const int wave = tid >> 6, lane = tid & 63;
  const int g = lane >> 4, r = lane & 15;

  // XCD-aware swizzle: 512 wgs, 8 XCDs -> 64 contiguous wgs per XCD
  const int wg = (blockIdx.x & 7) * 64 + (blockIdx.x >> 3);
  const int b = wg >> 7;                 // 128 wgs per batch
  const int nbase = (wg & 127) * 64;
  const f16* fhb = fh + (size_t)b * NN * CC;
  const int p0 = wave * 2;

  // --- stage 48 weight frags (Bm+W2) into LDS once ---
  f16x8 st[6];
#pragma unroll
  for (int i = 0; i < 6; ++i)
    st[i] = *(const f16x8*)(ws + (size_t)(i * 512 + tid) * 8);
#pragma unroll
  for (int i = 0; i < 6; ++i)
    *(f16x8*)(wbuf + (size_t)(i * 512 + tid) * 8) = st[i];

  // --- hoisted wave-constant frags: Aw (fA) and W3 (L3) ---
  f16x8 aw[2], w3f[4];
#pragma unroll
  for (int kt = 0; kt < 2; ++kt)
    aw[kt] = *(const f16x8*)(ws + (size_t)(48 + wave * 2 + kt) * 512 + lane * 8);
#pragma unroll
  for (int kt = 0; kt < 4; ++kt)
    w3f[kt] = *(const f16x8*)(ws + (size_t)(64 + wave * 4 + kt) * 512 + lane * 8);

  // --- prologue prefetch for iter 0 ---
  int nidx[2];
#pragma unroll
  for (int pp = 0; pp < 2; ++pp)
    nidx[pp] = knn[(size_t)(b * NN + nbase + p0 + pp) * KK + r];
  f16x8 bfa[2];          // own-point rows (fA B-frags), col r = point
  {
    const f16* fo16 = fhb + (size_t)(nbase + r) * CC;
    bfa[0] = *(const f16x8*)(fo16 + g * 8);
    bfa[1] = *(const f16x8*)(fo16 + 32 + g * 8);
  }
  f16x8 bf[2][2];        // neighbor rows (L1 B-frags)
#pragma unroll
  for (int pp = 0; pp < 2; ++pp) {
    const f16* fn16 = fhb + (size_t)nidx[pp] * CC;
#pragma unroll
    for (int kt = 0; kt < 2; ++kt)
      bf[pp][kt] = *(const f16x8*)(fn16 + kt * 32 + g * 8);
  }

  for (int it = 0; it < ITERS; ++it) {
    const int n0 = nbase + it * 16;
    const int itn = (it < ITERS - 1) ? it + 1 : it;

    // issue next-iter knn indices now (consumed at post-L2 prefetch point)
    int nidxN[2];
#pragma unroll
    for (int pp = 0; pp < 2; ++pp)
      nidxN[pp] = knn[(size_t)(b * NN + nbase + itn * 16 + p0 + pp) * KK + r];

    // --- fA: fa[wave's h-tile][all 16 pts] = f@Aw + b1 -> fabuf ---
    {
      f32x4 acc = {0.f, 0.f, 0.f, 0.f};
      acc = MFMA16(aw[0], bfa[0], acc);
      acc = MFMA16(aw[1], bfa[1], acc);
      f32x4 b1v = *(const f32x4*)(b1 + wave * 16 + g * 4);
      f32x4 fa;
#pragma unroll
      for (int i = 0; i < 4; ++i) fa[i] = acc[i] + b1v[i];
      *(f32x4*)(fabuf + r * 132 + wave * 16 + g * 4) = fa;
    }

    lds_barrier();   // (1) fabuf (+wbuf on iter 0) ready

    // --- L1: C[h][nbr] = Bm^T x knn (K=64), + fa broadcast -> h1 regs ---
    f16x8 h1f[2][4];
#pragma unroll
    for (int ht = 0; ht < 8; ++ht) {
      f32x4 acc[2] = {{0.f, 0.f, 0.f, 0.f}, {0.f, 0.f, 0.f, 0.f}};
#pragma unroll
      for (int kt = 0; kt < 2; ++kt) {
        f16x8 wfrag = *(const f16x8*)(wbuf + (size_t)(ht * 2 + kt) * 512 + lane * 8);
        acc[0] = MFMA16(wfrag, bf[0][kt], acc[0]);
        acc[1] = MFMA16(wfrag, bf[1][kt], acc[1]);
      }
      f32x4 fa0 = *(const f32x4*)(fabuf + (p0 + 0) * 132 + ht * 16 + g * 4);
      f32x4 fa1 = *(const f32x4*)(fabuf + (p0 + 1) * 132 + ht * 16 + g * 4);
#pragma unroll
      for (int pp = 0; pp < 2; ++pp) {
        const f32x4& fa = pp ? fa1 : fa0;
        float x0 = acc[pp][0] + fa[0]; x0 = x0 > 0.f ? x0 : 0.f;
        float x1 = acc[pp][1] + fa[1]; x1 = x1 > 0.f ? x1 : 0.f;
        float x2 = acc[pp][2] + fa[2]; x2 = x2 > 0.f ? x2 : 0.f;
        float x3 = acc[pp][3] + fa[3]; x3 = x3 > 0.f ? x3 : 0.f;
        h16x2 lo = __builtin_amdgcn_cvt_pkrtz(x0, x1);
        h16x2 hi = __builtin_amdgcn_cvt_pkrtz(x2, x3);
        h1f[pp][ht >> 1][(ht & 1) * 4 + 0] = (f16)lo[0];
        h1f[pp][ht >> 1][(ht & 1) * 4 + 1] = (f16)lo[1];
        h1f[pp][ht >> 1][(ht & 1) * 4 + 2] = (f16)hi[0];
        h1f[pp][ht >> 1][(ht & 1) * 4 + 3] = (f16)hi[1];
      }
    }

    // --- L2: C[nbr][h2] = h1 x W2; pool = 3 v_max + 2 shfl ---
#pragma unroll
    for (int h2t = 0; h2t < 8; ++h2t) {
      f32x4 c0 = {0.f, 0.f, 0.f, 0.f}, c1 = {0.f, 0.f, 0.f, 0.f};
#pragma unroll
      for (int kt = 0; kt < 4; ++kt) {
        f16x8 w2f = *(const f16x8*)(wbuf + (size_t)(16 + h2t * 4 + kt) * 512 + lane * 8);
        c0 = MFMA16(h1f[0][kt], w2f, c0);
        c1 = MFMA16(h1f[1][kt], w2f, c1);
      }
      float b2v = b2[h2t * 16 + r];
#pragma unroll
      for (int pp = 0; pp < 2; ++pp) {
        f32x4 cc = pp ? c1 : c0;
        float m = fmaxf(fmaxf(cc[0], cc[1]), fmaxf(cc[2], cc[3]));
        m = fmaxf(m, __shfl_xor(m, 16, 64));
        m = fmaxf(m, __shfl_xor(m, 32, 64));
        float x = m + b2v;
        f16 pv = (f16)(x > 0.f ? x : 0.f);
        if (g == 0) {
          pooled[(h2t >> 1) * 512 + ((r >> 2) * 16 + p0 + pp) * 8 +
                 (h2t & 1) * 4 + (r & 3)] = pv;
        }
      }
    }

    // --- T14: prefetch NEXT iter's own + neighbor f16 frags now ---
    f16x8 bfaN[2], bfN[2][2];
    {
      const f16* fo16 = fhb + (size_t)(nbase + itn * 16 + r) * CC;
      bfaN[0] = *(const f16x8*)(fo16 + g * 8);
      bfaN[1] = *(const f16x8*)(fo16 + 32 + g * 8);
    }
#pragma unroll
    for (int pp = 0; pp < 2; ++pp) {
      const f16* fn16 = fhb + (size_t)nidxN[pp] * CC;
#pragma unroll
      for (int kt = 0; kt < 2; ++kt)
        bfN[pp][kt] = *(const f16x8*)(fn16 + kt * 32 + g * 8);
    }

    lds_barrier();   // (2) pooled ready (cross-wave, LDS-only)

    // --- L3: C[od][pt] = W3^T x pooled; wave owns od-tile = wave ---
    {
      f32x4 a3 = {0.f, 0.f, 0.f, 0.f};
#pragma unroll
      for (int kt = 0; kt < 4; ++kt) {
        f16x8 pf = *(const f16x8*)(pooled + kt * 512 + lane * 8);
        a3 = MFMA16(w3f[kt], pf, a3);
      }
      f32x4 b3v = *(const f32x4*)(b3 + wave * 16 + g * 4);
      f32x4 o;
#pragma unroll
      for (int i = 0; i < 4; ++i) o[i] = a3[i] + b3v[i];
      *(f32x4*)(out + ((size_t)b * NN + n0 + r) * HH + wave * 16 + g * 4) = o;
    }

    // rotate prefetch state (constant indices only)
    bfa[0] = bfaN[0]; bfa[1] = bfaN[1];
#pragma unroll
    for (int pp = 0; pp < 2; ++pp)
#pragma unroll
      for (int kt = 0; kt < 2; ++kt)
        bf[pp][kt] = bfN[pp][kt];
    nidx[0] = nidxN[0]; nidx[1] = nidxN[1];
  }
}

// ---------------- fallback: exact r12 one-shot f32 path ----------------
__global__ __launch_bounds__(512, 4) void knn_fb(
    const float* __restrict__ f, const int* __restrict__ knn,
    const float* __restrict__ b1, const float* __restrict__ b2,
    const float* __restrict__ b3, const f16* __restrict__ ws,
    float* __restrict__ out) {
  extern __shared__ char smem[];
  f16* wbuf = (f16*)smem;
  float* fabuf = (float*)(wbuf + 48 * 512);
  f16* pooled = (f16*)(fabuf + 16 * 132);

  const int tid = threadIdx.x;
  const int wave = tid >> 6, lane = tid & 63;
  const int g = lane >> 4, r = lane & 15;
  const int wg = (blockIdx.x & 7) * 256 + (blockIdx.x >> 3);
  const int b = wg >> 9;
  const int n0 = (wg & 511) * 16;
  const float* fb = f + (size_t)b * NN * CC;
  const int p0 = wave * 2;

  int nidx[2];
#pragma unroll
  for (int pp = 0; pp < 2; ++pp)
    nidx[pp] = knn[(size_t)(b * NN + n0 + p0 + pp) * KK + r];

  const float* fo = fb + (size_t)(n0 + r) * CC;
  f32x4 rawF[2][2];
#pragma unroll
  for (int kt = 0; kt < 2; ++kt) {
    rawF[kt][0] = *(const f32x4*)(fo + kt * 32 + 4 * g);
    rawF[kt][1] = *(const f32x4*)(fo + kt * 32 + 4 * g + 16);
  }
  f16x8 aw[2];
#pragma unroll
  for (int kt = 0; kt < 2; ++kt)
    aw[kt] = *(const f16x8*)(ws + (size_t)(48 + wave * 2 + kt) * 512 + lane * 8);

  f16x8 st[6];
#pragma unroll
  for (int i = 0; i < 6; ++i)
    st[i] = *(const f16x8*)(ws + (size_t)(i * 512 + tid) * 8);
#pragma unroll
  for (int i = 0; i < 6; ++i)
    *(f16x8*)(wbuf + (size_t)(i * 512 + tid) * 8) = st[i];

  f32x4 rawN[2][2][2];
#pragma unroll
  for (int pp = 0; pp < 2; ++pp) {
    const float* fn = fb + (size_t)nidx[pp] * CC;
#pragma unroll
    for (int kt = 0; kt < 2; ++kt) {
      rawN[pp][kt][0] = *(const f32x4*)(fn + kt * 32 + 4 * g);
      rawN[pp][kt][1] = *(const f32x4*)(fn + kt * 32 + 4 * g + 16);
    }
  }

  {
    f32x4 acc = {0.f, 0.f, 0.f, 0.f};
#pragma unroll
    for (int kt = 0; kt < 2; ++kt) {
      f16x8 bfa2 = cvt8(rawF[kt][0], rawF[kt][1]);
      acc = MFMA16(aw[kt], bfa2, acc);
    }
    f32x4 b1v = *(const f32x4*)(b1 + wave * 16 + g * 4);
    f32x4 fa;
#pragma unroll
    for (int i = 0; i < 4; ++i) fa[i] = acc[i] + b1v[i];
    *(f32x4*)(fabuf + r * 132 + wave * 16 + g * 4) = fa;
  }

  lds_barrier();

  f16x8 bf[2][2];
#pragma unroll
  for (int pp = 0; pp < 2; ++pp)
#pragma unroll
    for (int kt = 0; kt < 2; ++kt)
      bf[pp][kt] = cvt8(rawN[pp][kt][0], rawN[pp][kt][1]);

  f16x8 h1f[2][4];
#pragma unroll
  for (int ht = 0; ht < 8; ++ht) {
    f32x4 acc[2] = {{0.f, 0.f, 0.f, 0.f}, {0.f, 0.f, 0.f, 0.f}};
#pragma unroll
    for (int kt = 0; kt < 2; ++kt) {
      f16x8 wfrag = *(const f16x8*)(wbuf + (size_t)(ht * 2 + kt) * 512 + lane * 8);
      acc[0] = MFMA16(wfrag, bf[0][kt], acc[0]);
      acc[1] = MFMA16(wfrag, bf[1][kt], acc[1]);
    }
    f32x4 fa0 = *(const f32x4*)(fabuf + (p0 + 0) * 132 + ht * 16 + g * 4);
    f32x4 fa1 = *(const f32x4*)(fabuf + (p0 + 1) * 132 + ht * 16 + g * 4);
#pragma unroll
    for (int pp = 0; pp < 2; ++pp) {
      const f32x4& fa = pp ? fa1 : fa0;
      float x0 = acc[pp][0] + fa[0]; x0 = x0 > 0.f ? x0 : 0.f;
      float x1 = acc[pp][1] + fa[1]; x1 = x1 > 0.f ? x1 : 0.f;
      float x2 = acc[pp][2] + fa[2]; x2 = x2 > 0.f ? x2 : 0.f;
      float x3 = acc[pp][3] + fa[3]; x3 = x3 > 0.f ? x3 : 0.f;
      h16x2 lo = __builtin_amdgcn_cvt_pkrtz(x0, x1);
      h16x2 hi = __builtin_amdgcn_cvt_pkrtz(x2, x3);
      h1f[pp][ht >> 1][(ht & 1) * 4 + 0] = (f16)lo[0];
      h1f[pp][ht >> 1][(ht & 1) * 4 + 1] = (f16)lo[1];
      h1f[pp][ht >> 1][(ht & 1) * 4 + 2] = (f16)hi[0];
      h1f[pp][ht >> 1][(ht & 1) * 4 + 3] = (f16)hi[1];
    }
  }

#pragma unroll
  for (int h2t = 0; h2t < 8; ++h2t) {
    f32x4 c0 = {0.f, 0.f, 0.f, 0.f}, c1 = {0.f, 0.f, 0.f, 0.f};
#pragma unroll
    for (int kt = 0; kt < 4; ++kt) {
      f16x8 w2f = *(const f16x8*)(wbuf + (size_t)(16 + h2t * 4 + kt) * 512 + lane * 8);
      c0 = MFMA16(h1f[0][kt], w2f, c0);
      c1 = MFMA16(h1f[1][kt], w2f, c1);
    }
    float b2v = b2[h2t * 16 + r];
#pragma unroll
    for (int pp = 0; pp < 2; ++pp) {
      f32x4 cc = pp ? c1 : c0;
      float m = fmaxf(fmaxf(cc[0], cc[1]), fmaxf(cc[2], cc[3]));
      m = fmaxf(m, __shfl_xor(m, 16, 64));
      m = fmaxf(m, __shfl_xor(m, 32, 64));
      float x = m + b2v;
      f16 pv = (f16)(x > 0.f ? x : 0.f);
      if (g == 0) {
        pooled[(h2t >> 1) * 512 + ((r >> 2) * 16 + p0 + pp) * 8 +
               (h2t & 1) * 4 + (r & 3)] = pv;
      }
    }
  }

  f16x8 w3f[4];
#pragma unroll
  for (int kt = 0; kt < 4; ++kt)
    w3f[kt] = *(const f16x8*)(ws + (size_t)(64 + wave * 4 + kt) * 512 + lane * 8);

  lds_barrier();

  {
    f32x4 a3 = {0.f, 0.f, 0.f, 0.f};
#pragma unroll
    for (int kt = 0; kt < 4; ++kt) {
      f16x8 pf = *(const f16x8*)(pooled + kt * 512 + lane * 8);
      a3 = MFMA16(w3f[kt], pf, a3);
    }
    f32x4 b3v = *(const f32x4*)(b3 + wave * 16 + g * 4);
    f32x4 o;
#pragma unroll
    for (int i = 0; i < 4; ++i) o[i] = a3[i] + b3v[i];
    *(f32x4*)(out + ((size_t)b * NN + n0 + r) * HH + wave * 16 + g * 4) = o;
  }
}

extern "C" void kernel_launch(void* const* d_in, const int* in_sizes, int n_in,
                              void* d_out, int out_size, void* d_ws, size_t ws_size,
                              hipStream_t stream) {
  const float* f = (const float*)d_in[0];
  const int* knn = (const int*)d_in[1];
  const float* W1 = (const float*)d_in[2];
  const float* b1 = (const float*)d_in[3];
  const float* W2 = (const float*)d_in[4];
  const float* b2 = (const float*)d_in[5];
  const float* W3 = (const float*)d_in[6];
  const float* b3 = (const float*)d_in[7];
  float* outp = (float*)d_out;
  f16* wsp = (f16*)d_ws;                 // frags: 96KB; fh: +4MB after
  f16* fh = wsp + 96 * 512;

  const size_t need = 96 * 1024 + (size_t)BB * NN * CC * 2;

  if (ws_size >= need) {
    (void)hipFuncSetAttribute((const void*)knn_pers,
                              hipFuncAttributeMaxDynamicSharedMemorySize, 61696);
    prep_all<<<12 + (BB * NN * 8) / 512, 512, 0, stream>>>(f, W1, W2, W3, wsp, fh);
    // 64 pts/block (4 iters x 16) -> grid = 32768/64 = 512 = 2 blocks/CU
    knn_pers<<<(BB * NN) / 64, 512, 61696, stream>>>(knn, b1, b2, b3, wsp, fh, outp);
  } else {
    (void)hipFuncSetAttribute((const void*)knn_fb,
                              hipFuncAttributeMaxDynamicSharedMemorySize, 61696);
    prep_all<<<12, 512, 0, stream>>>(f, W1, W2, W3, wsp, fh);
    knn_fb<<<(BB * NN) / 16, 512, 61696, stream>>>(f, knn, b1, b2, b3, wsp, outp);
  }
}